// Round 11
// baseline (147.669 us; speedup 1.0000x reference)
//
#include <hip/hip_runtime.h>
#include <hip/hip_bf16.h>
#include <cstdint>

// Shapes fixed by the reference: B=4, T=2048, D=512, H=8, hd=64, MAX_RADIUS=16.
// Session lessons:
//  - R5/R6: in-kernel device-scope fences ~200us -> kernel boundaries are the
//    coherence mechanism; multi-launch structure.
//  - R1->R2: per-launch overhead ~4us. R8: BK=128 LDS-occupancy cliff.
//  - R2..R10: GEMM-internals knobs all neutral (+-3us noise) -> attack fixed
//    costs: R11 removes the cast launch + HBM round-trip by staging f32
//    operands and packing to bf16 in-register (v_perm_b32 RTZ, 1 inst/pair).
#define T_LEN 2048
#define B_SZ 4
#define D_MOD 512
#define N_HEAD 8
#define HDIM 64
#define QKV_N 1536
#define M_ROWS 8192   // B*T
#define BK 64

typedef uint32_t u32;
typedef uint16_t u16;
typedef __attribute__((ext_vector_type(8))) __bf16 bf16x8;
typedef __attribute__((ext_vector_type(4))) float f32x4;

__device__ __forceinline__ u16 f2bf(float f) {   // RNE (epilogue only)
    u32 u = __builtin_bit_cast(u32, f);
    u32 r = (u + 0x7FFFu + ((u >> 16) & 1u)) >> 16;
    return (u16)r;
}
__device__ __forceinline__ float bf2f(u16 h) {
    u32 u = ((u32)h) << 16;
    return __builtin_bit_cast(float, u);
}

// pack 8 f32 -> bf16x8 via v_perm_b32 (RTZ: top 16 bits). 4 inst total.
// Fallback if absmax regresses: add 0x8000 to each u32 first (round-half-up).
__device__ __forceinline__ bf16x8 pack8(float4 lo, float4 hi) {
    union { u32 u[4]; bf16x8 v; } r;
    r.u[0] = __builtin_amdgcn_perm(__builtin_bit_cast(u32, lo.y), __builtin_bit_cast(u32, lo.x), 0x07060302u);
    r.u[1] = __builtin_amdgcn_perm(__builtin_bit_cast(u32, lo.w), __builtin_bit_cast(u32, lo.z), 0x07060302u);
    r.u[2] = __builtin_amdgcn_perm(__builtin_bit_cast(u32, hi.y), __builtin_bit_cast(u32, hi.x), 0x07060302u);
    r.u[3] = __builtin_amdgcn_perm(__builtin_bit_cast(u32, hi.w), __builtin_bit_cast(u32, hi.z), 0x07060302u);
    return r.v;
}

// ========== GEMM1: qkv[8192,1536] = x[8192,512](f32) * w_in[1536,512]^T(f32) + b_in ==========
// 128x128 tile, BK=64, f32 LDS staging both operands (32+32 KB -> 2 blocks/CU).
// f32 row = 16 x 16B chunks; chunk c of row r stored at position c^(r&15)
// (global_load_lds uniform-base + lane*16; 4 rows x 16 slots per issue).
// Fragment g=fq^(kh<<2) of row r: chunks {2g,2g+1} at positions {(2g)^(r&15), ^1}
// -> two float4 reads, lane base bank spans all 32 banks, 2-way = free.
// Operand-swapped MFMA: lane (fr,fq) holds C[mi*16+fr][ni*16+fq*4+rr].
__global__ __launch_bounds__(256, 2)
void gemm1_f32(const float* __restrict__ A, const float* __restrict__ B,
               const float* __restrict__ bias, u16* __restrict__ C,
               int M, int N, int K)
{
    __shared__ alignas(16) float ldaf[128 * BK];
    __shared__ alignas(16) float ldbf[128 * BK];
    const int tid  = threadIdx.x;
    const int wave = tid >> 6;
    const int lane = tid & 63;
    const int bn = blockIdx.x, bm = blockIdx.y;
    const int wm = wave >> 1, wn = wave & 1;

    f32x4 acc[4][4] = {};

    const int srow4 = lane >> 4;               // row within 4-row issue group
    const int slot  = lane & 15;               // 16B chunk slot within row
    const long a_base = (long)bm * 128;
    const long b_base = (long)bn * 128;
    const int fr = lane & 15;
    const int fq = lane >> 4;

    for (int kk = 0; kk < K; kk += BK) {
#pragma unroll
        for (int j = 0; j < 8; ++j) {          // A: 32 rows/wave, 4 rows/issue
            int rloc = j * 4 + srow4;
            int gc = slot ^ (rloc & 15);
            int r = wave * 32 + rloc;
            const float* ga = A + (a_base + r) * (long)K + kk + gc * 4;
            __builtin_amdgcn_global_load_lds(
                (const __attribute__((address_space(1))) void*)ga,
                (__attribute__((address_space(3))) void*)&ldaf[(wave * 32 + j * 4) * BK],
                16, 0, 0);
        }
#pragma unroll
        for (int j = 0; j < 8; ++j) {          // B: same scheme
            int rloc = j * 4 + srow4;
            int gc = slot ^ (rloc & 15);
            int r = wave * 32 + rloc;
            const float* gb = B + (b_base + r) * (long)K + kk + gc * 4;
            __builtin_amdgcn_global_load_lds(
                (const __attribute__((address_space(1))) void*)gb,
                (__attribute__((address_space(3))) void*)&ldbf[(wave * 32 + j * 4) * BK],
                16, 0, 0);
        }
        __syncthreads();
#pragma unroll
        for (int kh = 0; kh < 2; ++kh) {
            bf16x8 af[4], bfr[4];
#pragma unroll
            for (int i = 0; i < 4; ++i) {
                int ra = wm * 64 + i * 16 + fr;
                int c0 = ((fq << 1) ^ (kh << 3)) ^ (ra & 15);
                float4 lo = *(const float4*)&ldaf[ra * BK + c0 * 4];
                float4 hi = *(const float4*)&ldaf[ra * BK + (c0 ^ 1) * 4];
                af[i] = pack8(lo, hi);
            }
#pragma unroll
            for (int i = 0; i < 4; ++i) {
                int rb = wn * 64 + i * 16 + fr;
                int c0 = ((fq << 1) ^ (kh << 3)) ^ (rb & 15);
                float4 lo = *(const float4*)&ldbf[rb * BK + c0 * 4];
                float4 hi = *(const float4*)&ldbf[rb * BK + (c0 ^ 1) * 4];
                bfr[i] = pack8(lo, hi);
            }
#pragma unroll
            for (int mi = 0; mi < 4; ++mi)
#pragma unroll
                for (int ni = 0; ni < 4; ++ni)
                    acc[mi][ni] = __builtin_amdgcn_mfma_f32_16x16x32_bf16(
                        bfr[ni], af[mi], acc[mi][ni], 0, 0, 0);   // swapped -> C^T regs
        }
        __syncthreads();
    }

    const long row0 = a_base + wm * 64;
    const long col0 = b_base + wn * 64;
#pragma unroll
    for (int mi = 0; mi < 4; ++mi) {
        long row = row0 + mi * 16 + fr;
#pragma unroll
        for (int ni = 0; ni < 4; ++ni) {
            long col = col0 + ni * 16 + fq * 4;
            float4 bv = *(const float4*)&bias[col];
            u32 lo = (u32)f2bf(acc[mi][ni][0] + bv.x) | ((u32)f2bf(acc[mi][ni][1] + bv.y) << 16);
            u32 hi = (u32)f2bf(acc[mi][ni][2] + bv.z) | ((u32)f2bf(acc[mi][ni][3] + bv.w) << 16);
            *(uint2*)(C + row * (long)N + col) = make_uint2(lo, hi);
        }
    }
}

// ========== GEMM2: out[8192,512](f32) = attn[8192,512](bf16) * w_out[512,512]^T(f32) + b_out ==========
// 64x128 tile; A bf16 (8KB, 8-chunk rows, key r&7), B f32 (32KB, as GEMM1) -> 40KB, 4 blocks/CU.
__global__ __launch_bounds__(256, 3)
void gemm2_mix(const u16* __restrict__ A, const float* __restrict__ B,
               const float* __restrict__ bias, float* __restrict__ C,
               int M, int N, int K)
{
    __shared__ alignas(16) u16   lda16[64 * BK];
    __shared__ alignas(16) float ldbf[128 * BK];
    const int tid  = threadIdx.x;
    const int wave = tid >> 6;
    const int lane = tid & 63;
    const int bn = blockIdx.x, bm = blockIdx.y;
    const int wm = wave >> 1, wn = wave & 1;

    f32x4 acc[2][4] = {};

    const int srow8 = lane >> 3;               // bf16 staging: 8 rows/issue
    const int slot8 = lane & 7;
    const int srow4 = lane >> 4;               // f32 staging: 4 rows/issue
    const int slot16 = lane & 15;
    const long a_base = (long)bm * 64;
    const long b_base = (long)bn * 128;
    const int fr = lane & 15;
    const int fq = lane >> 4;

    for (int kk = 0; kk < K; kk += BK) {
#pragma unroll
        for (int j = 0; j < 2; ++j) {          // A bf16: 16 rows/wave
            int rloc = j * 8 + srow8;
            int gc = slot8 ^ (rloc & 7);
            int r = wave * 16 + rloc;
            const u16* ga = A + (a_base + r) * (long)K + kk + gc * 8;
            __builtin_amdgcn_global_load_lds(
                (const __attribute__((address_space(1))) void*)ga,
                (__attribute__((address_space(3))) void*)&lda16[(wave * 16 + j * 8) * BK],
                16, 0, 0);
        }
#pragma unroll
        for (int j = 0; j < 8; ++j) {          // B f32: 32 rows/wave
            int rloc = j * 4 + srow4;
            int gc = slot16 ^ (rloc & 15);
            int r = wave * 32 + rloc;
            const float* gb = B + (b_base + r) * (long)K + kk + gc * 4;
            __builtin_amdgcn_global_load_lds(
                (const __attribute__((address_space(1))) void*)gb,
                (__attribute__((address_space(3))) void*)&ldbf[(wave * 32 + j * 4) * BK],
                16, 0, 0);
        }
        __syncthreads();
#pragma unroll
        for (int kh = 0; kh < 2; ++kh) {
            bf16x8 af[2], bfr[4];
#pragma unroll
            for (int i = 0; i < 2; ++i) {
                int ra = wm * 32 + i * 16 + fr;
                af[i] = *(const bf16x8*)&lda16[(ra * BK + ((fq ^ (ra & 7)) * 8)) ^ (kh << 5)];
            }
#pragma unroll
            for (int i = 0; i < 4; ++i) {
                int rb = wn * 64 + i * 16 + fr;
                int c0 = ((fq << 1) ^ (kh << 3)) ^ (rb & 15);
                float4 lo = *(const float4*)&ldbf[rb * BK + c0 * 4];
                float4 hi = *(const float4*)&ldbf[rb * BK + (c0 ^ 1) * 4];
                bfr[i] = pack8(lo, hi);
            }
#pragma unroll
            for (int mi = 0; mi < 2; ++mi)
#pragma unroll
                for (int ni = 0; ni < 4; ++ni)
                    acc[mi][ni] = __builtin_amdgcn_mfma_f32_16x16x32_bf16(
                        bfr[ni], af[mi], acc[mi][ni], 0, 0, 0);
        }
        __syncthreads();
    }

    const long row0 = a_base + wm * 32;
    const long col0 = b_base + wn * 64;
#pragma unroll
    for (int mi = 0; mi < 2; ++mi) {
        long row = row0 + mi * 16 + fr;
#pragma unroll
        for (int ni = 0; ni < 4; ++ni) {
            long col = col0 + ni * 16 + fq * 4;
            float4 bv = *(const float4*)&bias[col];
            *(float4*)(C + row * (long)N + col) = make_float4(
                acc[mi][ni][0] + bv.x, acc[mi][ni][1] + bv.y,
                acc[mi][ni][2] + bv.z, acc[mi][ni][3] + bv.w);
        }
    }
}

// ---------------- banded attention, query-pair version (R2..R10-proven) ----------------
#define AQ 128
#define AW 16
#define AROWS (AQ + 2 * AW)   // 160
#define ASTR 70

__device__ __forceinline__ void unpack16(const u32* __restrict__ src, float* __restrict__ dst) {
#pragma unroll
    for (int dd = 0; dd < 8; ++dd) {
        u32 wv = src[dd];
        dst[2 * dd]     = bf2f((u16)(wv & 0xffffu));
        dst[2 * dd + 1] = bf2f((u16)(wv >> 16));
    }
}

__global__ __launch_bounds__(256)
void attn_kernel(const u16* __restrict__ qkv, const float* __restrict__ radius,
                 u16* __restrict__ out)
{
    __shared__ u16 ks[AROWS * ASTR];
    __shared__ u16 vs[AROWS * ASTR];

    const int tid = threadIdx.x;
    const int bid = blockIdx.x;
    const int qc = bid & 15;
    const int h  = (bid >> 4) & 7;
    const int b  = bid >> 7;
    const int q0 = qc * AQ;

    float rad = radius[h];
    float r = fmaxf(16.0f / (1.0f + __expf(-rad)), 1.0f);
    const int w = (int)floorf(r);       // 1..15

    for (int cid = tid; cid < AROWS * 4; cid += 256) {
        int row = cid >> 2;
        int ch  = cid & 3;
        int t = min(max(q0 - AW + row, 0), T_LEN - 1);
        const u16* gk = qkv + ((long)(b * T_LEN + t)) * QKV_N + D_MOD + h * HDIM + ch * 16;
        const u16* gv = gk + D_MOD;
        uint4 k0 = *(const uint4*)gk, k1 = *(const uint4*)(gk + 8);
        uint4 v0 = *(const uint4*)gv, v1 = *(const uint4*)(gv + 8);
        u32* kd = (u32*)&ks[row * ASTR + ch * 18];
        u32* vd = (u32*)&vs[row * ASTR + ch * 18];
        kd[0] = k0.x; kd[1] = k0.y; kd[2] = k0.z; kd[3] = k0.w;
        kd[4] = k1.x; kd[5] = k1.y; kd[6] = k1.z; kd[7] = k1.w;
        vd[0] = v0.x; vd[1] = v0.y; vd[2] = v0.z; vd[3] = v0.w;
        vd[4] = v1.x; vd[5] = v1.y; vd[6] = v1.z; vd[7] = v1.w;
    }

    const int p = tid >> 2;          // pair index 0..63
    const int g = tid & 3;           // dim group (16 dims)
    const int qA = q0 + 2 * p;
    const long rowA = (long)(b * T_LEN + qA);
    const long rowB = rowA + 1;

    float qregA[16], qregB[16];
    {
        const u16* gq = qkv + rowA * QKV_N + h * HDIM + g * 16;
        u32 wa[8], wb[8];
        uint4 t0 = *(const uint4*)gq,              t1 = *(const uint4*)(gq + 8);
        uint4 t2 = *(const uint4*)(gq + QKV_N),    t3 = *(const uint4*)(gq + QKV_N + 8);
        wa[0]=t0.x; wa[1]=t0.y; wa[2]=t0.z; wa[3]=t0.w; wa[4]=t1.x; wa[5]=t1.y; wa[6]=t1.z; wa[7]=t1.w;
        wb[0]=t2.x; wb[1]=t2.y; wb[2]=t2.z; wb[3]=t2.w; wb[4]=t3.x; wb[5]=t3.y; wb[6]=t3.z; wb[7]=t3.w;
#pragma unroll
        for (int j = 0; j < 8; ++j) {
            qregA[2 * j]     = bf2f((u16)(wa[j] & 0xffffu)) * 0.125f;
            qregA[2 * j + 1] = bf2f((u16)(wa[j] >> 16))     * 0.125f;
            qregB[2 * j]     = bf2f((u16)(wb[j] & 0xffffu)) * 0.125f;
            qregB[2 * j + 1] = bf2f((u16)(wb[j] >> 16))     * 0.125f;
        }
    }
    __syncthreads();

    float mA = -1e30f, lA = 0.0f, mB = -1e30f, lB = 0.0f;
    float accA[16], accB[16];
#pragma unroll
    for (int d = 0; d < 16; ++d) { accA[d] = 0.0f; accB[d] = 0.0f; }

    const int imax = 2 * w + 1;
    for (int i = 0; i <= imax; ++i) {
        int jrow = 2 * p - w + i;
        int j = q0 + jrow;
        int row = jrow + AW;
        float kf[16];
        unpack16((const u32*)&ks[row * ASTR + g * 18], kf);
        float sA = 0.0f, sB = 0.0f;
#pragma unroll
        for (int d = 0; d < 16; ++d) { sA += qregA[d] * kf[d]; sB += qregB[d] * kf[d]; }
        sA += __shfl_xor(sA, 1); sA += __shfl_xor(sA, 2);
        sB += __shfl_xor(sB, 1); sB += __shfl_xor(sB, 2);
        bool inb = ((unsigned)j) < (unsigned)T_LEN;
        bool vA = inb && (i < imax);
        bool vB = inb && (i > 0);
        float mnA = fmaxf(mA, vA ? sA : -1e30f);
        float scA = __expf(mA - mnA);
        float pA  = vA ? __expf(sA - mnA) : 0.0f;
        mA = mnA; lA = lA * scA + pA;
        float mnB = fmaxf(mB, vB ? sB : -1e30f);
        float scB = __expf(mB - mnB);
        float pB  = vB ? __expf(sB - mnB) : 0.0f;
        mB = mnB; lB = lB * scB + pB;
        float vf[16];
        unpack16((const u32*)&vs[row * ASTR + g * 18], vf);
#pragma unroll
        for (int d = 0; d < 16; ++d) {
            accA[d] = accA[d] * scA + pA * vf[d];
            accB[d] = accB[d] * scB + pB * vf[d];
        }
    }

    float invA = 1.0f / lA;
    float invB = 1.0f / lB;
    u32 oA[8], oB[8];
#pragma unroll
    for (int j2 = 0; j2 < 8; ++j2) {
        oA[j2] = (u32)f2bf(accA[2 * j2] * invA) | ((u32)f2bf(accA[2 * j2 + 1] * invA) << 16);
        oB[j2] = (u32)f2bf(accB[2 * j2] * invB) | ((u32)f2bf(accB[2 * j2 + 1] * invB) << 16);
    }
    u16* poA = out + rowA * D_MOD + h * HDIM + g * 16;
    u16* poB = out + rowB * D_MOD + h * HDIM + g * 16;
    *(uint4*)poA       = make_uint4(oA[0], oA[1], oA[2], oA[3]);
    *(uint4*)(poA + 8) = make_uint4(oA[4], oA[5], oA[6], oA[7]);
    *(uint4*)poB       = make_uint4(oB[0], oB[1], oB[2], oB[3]);
    *(uint4*)(poB + 8) = make_uint4(oB[4], oB[5], oB[6], oB[7]);
}

// ---------------- launch: 3 kernels, no cast phase ----------------
extern "C" void kernel_launch(void* const* d_in, const int* in_sizes, int n_in,
                              void* d_out, int out_size, void* d_ws, size_t ws_size,
                              hipStream_t stream)
{
    (void)in_sizes; (void)n_in; (void)out_size; (void)ws_size;
    const float* x      = (const float*)d_in[0];
    const float* radius = (const float*)d_in[1];
    const float* w_in   = (const float*)d_in[2];
    const float* b_in   = (const float*)d_in[3];
    const float* w_out  = (const float*)d_in[4];
    const float* b_out  = (const float*)d_in[5];
    float* outp = (float*)d_out;

    char* ws = (char*)d_ws;
    u16* qkv_bf  = (u16*)ws;  ws += (size_t)M_ROWS * QKV_N * 2;   // 25 MB
    u16* attn_bf = (u16*)ws;                                      // 8 MB

    gemm1_f32<<<dim3(QKV_N / 128, M_ROWS / 128), 256, 0, stream>>>(
        x, w_in, b_in, qkv_bf, M_ROWS, QKV_N, D_MOD);
    attn_kernel<<<B_SZ * N_HEAD * (T_LEN / AQ), 256, 0, stream>>>(qkv_bf, radius, attn_bf);
    gemm2_mix<<<dim3(D_MOD / 128, M_ROWS / 64), 256, 0, stream>>>(
        attn_bf, w_out, b_out, outp, M_ROWS, D_MOD, D_MOD);
}

// Round 12
// 127.897 us; speedup vs baseline: 1.1546x; 1.1546x over previous
//
#include <hip/hip_runtime.h>
#include <hip/hip_bf16.h>
#include <cstdint>

// Shapes fixed by the reference: B=4, T=2048, D=512, H=8, hd=64, MAX_RADIUS=16.
// FINAL (R12 = revert to R7, session best 126.7us). Session evidence:
//  - R5/R6: in-kernel device-scope fences ~200us (full-L2 wb/inv per block);
//    kernel-launch boundaries are the cheap coherence mechanism -> 4-launch plan.
//  - R8: BK=128 LDS-occupancy cliff. R11: f32 staging doubles issue count +
//    LDS, pack8 on critical path -> gemm1 44us @ MfmaUtil 10% (direct counter
//    evidence of the latency-bound plateau). bf16 cast pipeline is right.
//  - R2..R10: all GEMM-internals knobs neutral within +-3us noise; the m97-family
//    plateau + ~60us harness reset floor dominate.
#define T_LEN 2048
#define B_SZ 4
#define D_MOD 512
#define N_HEAD 8
#define HDIM 64
#define QKV_N 1536
#define M_ROWS 8192   // B*T

typedef uint32_t u32;
typedef uint16_t u16;
typedef __attribute__((ext_vector_type(8))) __bf16 bf16x8;
typedef __attribute__((ext_vector_type(4))) float f32x4;

__device__ __forceinline__ u16 f2bf(float f) {
    u32 u = __builtin_bit_cast(u32, f);
    u32 r = (u + 0x7FFFu + ((u >> 16) & 1u)) >> 16;   // RNE
    return (u16)r;
}
__device__ __forceinline__ float bf2f(u16 h) {
    u32 u = ((u32)h) << 16;
    return __builtin_bit_cast(float, u);
}

// ---------------- fused cast f32 -> bf16 for all three inputs ----------------
__global__ void cast3_kernel(const float* __restrict__ a, int na,
                             const float* __restrict__ b, int nb,
                             const float* __restrict__ c,
                             u16* __restrict__ oa, u16* __restrict__ ob, u16* __restrict__ oc) {
    int i8 = (blockIdx.x * blockDim.x + threadIdx.x) * 8;
    const float* src; u16* dst; int off;
    if (i8 < na)           { src = a; dst = oa; off = i8; }
    else if (i8 < na + nb) { src = b; dst = ob; off = i8 - na; }
    else                   { src = c; dst = oc; off = i8 - na - nb; }
    const float4* p = (const float4*)(src + off);
    float4 x = p[0], y = p[1];
    u32 r0 = (u32)f2bf(x.x) | ((u32)f2bf(x.y) << 16);
    u32 r1 = (u32)f2bf(x.z) | ((u32)f2bf(x.w) << 16);
    u32 r2 = (u32)f2bf(y.x) | ((u32)f2bf(y.y) << 16);
    u32 r3 = (u32)f2bf(y.z) | ((u32)f2bf(y.w) << 16);
    *(uint4*)(dst + off) = make_uint4(r0, r1, r2, r3);
}

// ---------------- GEMM: C[M,N] = A[M,K] * B[N,K]^T + bias, bf16 in ----------------
// BK=64, 4 waves 2x2, wave tile (BMt/2)x(BNt/2). GEMM1: 128x192 (512 tiles);
// GEMM2: 64x128. Staging: lane l stages global 16B chunk (l&7)^(l>>3) of its
// 8-row group at linear LDS chunk l; fragment chunk G=kh*4+fq of row r at LDS
// chunk G^(r&7) -> offset = base ^ (kh<<5); 2-way bank spread = free (m136).
#define BK 64

template <bool OUT_BF16, int BMt, int BNt>
__global__ __launch_bounds__(256, 2)
void gemm_bt(const u16* __restrict__ A, const u16* __restrict__ B,
             const float* __restrict__ bias, void* __restrict__ C,
             int M, int N, int K)
{
    constexpr int WM = BMt / 2;
    constexpr int WN = BNt / 2;
    constexpr int MI = WM / 16;
    constexpr int NI = WN / 16;
    __shared__ alignas(16) u16 lda[BMt * BK];
    __shared__ alignas(16) u16 ldb[BNt * BK];
    const int tid  = threadIdx.x;
    const int wave = tid >> 6;
    const int lane = tid & 63;
    const int bn = blockIdx.x, bm = blockIdx.y;
    const int wm = wave >> 1, wn = wave & 1;

    f32x4 acc[MI][NI] = {};

    const int srow8 = lane >> 3;               // 0..7 row within 8-row group
    const int sg    = (lane & 7) ^ srow8;      // swizzled global 8-elem chunk
    const long a_base = (long)bm * BMt;
    const long b_base = (long)bn * BNt;

    const int fr = lane & 15;
    const int fq = lane >> 4;
    int a_off[MI], b_off[NI];
#pragma unroll
    for (int i = 0; i < MI; ++i) {
        int ra = wm * WM + i * 16 + fr;
        a_off[i] = ra * BK + ((fq ^ (ra & 7)) * 8);
    }
#pragma unroll
    for (int i = 0; i < NI; ++i) {
        int rb = wn * WN + i * 16 + fr;
        b_off[i] = rb * BK + ((fq ^ (rb & 7)) * 8);
    }

    for (int kk = 0; kk < K; kk += BK) {
#pragma unroll
        for (int j = 0; j < BMt / 32; ++j) {
            int r = wave * (BMt / 4) + j * 8 + srow8;
            const u16* ga = A + (a_base + r) * (long)K + kk + sg * 8;
            __builtin_amdgcn_global_load_lds(
                (const __attribute__((address_space(1))) void*)ga,
                (__attribute__((address_space(3))) void*)&lda[(wave * (BMt / 4) + j * 8) * BK],
                16, 0, 0);
        }
#pragma unroll
        for (int j = 0; j < BNt / 32; ++j) {
            int r = wave * (BNt / 4) + j * 8 + srow8;
            const u16* gb = B + (b_base + r) * (long)K + kk + sg * 8;
            __builtin_amdgcn_global_load_lds(
                (const __attribute__((address_space(1))) void*)gb,
                (__attribute__((address_space(3))) void*)&ldb[(wave * (BNt / 4) + j * 8) * BK],
                16, 0, 0);
        }
        __syncthreads();
#pragma unroll
        for (int kh = 0; kh < 2; ++kh) {
            bf16x8 af[MI], bfr[NI];
#pragma unroll
            for (int i = 0; i < MI; ++i) af[i]  = *(const bf16x8*)&lda[a_off[i] ^ (kh << 5)];
#pragma unroll
            for (int i = 0; i < NI; ++i) bfr[i] = *(const bf16x8*)&ldb[b_off[i] ^ (kh << 5)];
#pragma unroll
            for (int mi = 0; mi < MI; ++mi)
#pragma unroll
                for (int ni = 0; ni < NI; ++ni)
                    acc[mi][ni] = __builtin_amdgcn_mfma_f32_16x16x32_bf16(
                        af[mi], bfr[ni], acc[mi][ni], 0, 0, 0);
        }
        __syncthreads();
    }

    // epilogue: C/D layout col=lane&15, row=(lane>>4)*4+reg (m89-verified)
    const long row0 = a_base + wm * WM;
    const long col0 = b_base + wn * WN;
#pragma unroll
    for (int mi = 0; mi < MI; ++mi) {
#pragma unroll
        for (int ni = 0; ni < NI; ++ni) {
            long col = col0 + ni * 16 + fr;
            float bv = bias[col];
            long rowb = row0 + mi * 16 + fq * 4;
#pragma unroll
            for (int rr = 0; rr < 4; ++rr) {
                float v = acc[mi][ni][rr] + bv;
                long idx = (rowb + rr) * (long)N + col;
                if (OUT_BF16) ((u16*)C)[idx] = f2bf(v);
                else          ((float*)C)[idx] = v;
            }
        }
    }
}

// ---------------- banded attention, query-pair version (R2..R10-proven) ----------------
#define AQ 128
#define AW 16
#define AROWS (AQ + 2 * AW)   // 160
#define ASTR 70

__device__ __forceinline__ void unpack16(const u32* __restrict__ src, float* __restrict__ dst) {
#pragma unroll
    for (int dd = 0; dd < 8; ++dd) {
        u32 wv = src[dd];
        dst[2 * dd]     = bf2f((u16)(wv & 0xffffu));
        dst[2 * dd + 1] = bf2f((u16)(wv >> 16));
    }
}

__global__ __launch_bounds__(256)
void attn_kernel(const u16* __restrict__ qkv, const float* __restrict__ radius,
                 u16* __restrict__ out)
{
    __shared__ u16 ks[AROWS * ASTR];
    __shared__ u16 vs[AROWS * ASTR];

    const int tid = threadIdx.x;
    const int bid = blockIdx.x;
    const int qc = bid & 15;
    const int h  = (bid >> 4) & 7;
    const int b  = bid >> 7;
    const int q0 = qc * AQ;

    float rad = radius[h];
    float r = fmaxf(16.0f / (1.0f + __expf(-rad)), 1.0f);
    const int w = (int)floorf(r);       // 1..15

    for (int cid = tid; cid < AROWS * 4; cid += 256) {
        int row = cid >> 2;
        int ch  = cid & 3;
        int t = min(max(q0 - AW + row, 0), T_LEN - 1);
        const u16* gk = qkv + ((long)(b * T_LEN + t)) * QKV_N + D_MOD + h * HDIM + ch * 16;
        const u16* gv = gk + D_MOD;
        uint4 k0 = *(const uint4*)gk, k1 = *(const uint4*)(gk + 8);
        uint4 v0 = *(const uint4*)gv, v1 = *(const uint4*)(gv + 8);
        u32* kd = (u32*)&ks[row * ASTR + ch * 18];
        u32* vd = (u32*)&vs[row * ASTR + ch * 18];
        kd[0] = k0.x; kd[1] = k0.y; kd[2] = k0.z; kd[3] = k0.w;
        kd[4] = k1.x; kd[5] = k1.y; kd[6] = k1.z; kd[7] = k1.w;
        vd[0] = v0.x; vd[1] = v0.y; vd[2] = v0.z; vd[3] = v0.w;
        vd[4] = v1.x; vd[5] = v1.y; vd[6] = v1.z; vd[7] = v1.w;
    }

    const int p = tid >> 2;          // pair index 0..63
    const int g = tid & 3;           // dim group (16 dims)
    const int qA = q0 + 2 * p;
    const long rowA = (long)(b * T_LEN + qA);
    const long rowB = rowA + 1;

    float qregA[16], qregB[16];
    {
        const u16* gq = qkv + rowA * QKV_N + h * HDIM + g * 16;
        u32 wa[8], wb[8];
        uint4 t0 = *(const uint4*)gq,              t1 = *(const uint4*)(gq + 8);
        uint4 t2 = *(const uint4*)(gq + QKV_N),    t3 = *(const uint4*)(gq + QKV_N + 8);
        wa[0]=t0.x; wa[1]=t0.y; wa[2]=t0.z; wa[3]=t0.w; wa[4]=t1.x; wa[5]=t1.y; wa[6]=t1.z; wa[7]=t1.w;
        wb[0]=t2.x; wb[1]=t2.y; wb[2]=t2.z; wb[3]=t2.w; wb[4]=t3.x; wb[5]=t3.y; wb[6]=t3.z; wb[7]=t3.w;
#pragma unroll
        for (int j = 0; j < 8; ++j) {
            qregA[2 * j]     = bf2f((u16)(wa[j] & 0xffffu)) * 0.125f;
            qregA[2 * j + 1] = bf2f((u16)(wa[j] >> 16))     * 0.125f;
            qregB[2 * j]     = bf2f((u16)(wb[j] & 0xffffu)) * 0.125f;
            qregB[2 * j + 1] = bf2f((u16)(wb[j] >> 16))     * 0.125f;
        }
    }
    __syncthreads();

    float mA = -1e30f, lA = 0.0f, mB = -1e30f, lB = 0.0f;
    float accA[16], accB[16];
#pragma unroll
    for (int d = 0; d < 16; ++d) { accA[d] = 0.0f; accB[d] = 0.0f; }

    const int imax = 2 * w + 1;
    for (int i = 0; i <= imax; ++i) {
        int jrow = 2 * p - w + i;
        int j = q0 + jrow;
        int row = jrow + AW;
        float kf[16];
        unpack16((const u32*)&ks[row * ASTR + g * 18], kf);
        float sA = 0.0f, sB = 0.0f;
#pragma unroll
        for (int d = 0; d < 16; ++d) { sA += qregA[d] * kf[d]; sB += qregB[d] * kf[d]; }
        sA += __shfl_xor(sA, 1); sA += __shfl_xor(sA, 2);
        sB += __shfl_xor(sB, 1); sB += __shfl_xor(sB, 2);
        bool inb = ((unsigned)j) < (unsigned)T_LEN;
        bool vA = inb && (i < imax);
        bool vB = inb && (i > 0);
        float mnA = fmaxf(mA, vA ? sA : -1e30f);
        float scA = __expf(mA - mnA);
        float pA  = vA ? __expf(sA - mnA) : 0.0f;
        mA = mnA; lA = lA * scA + pA;
        float mnB = fmaxf(mB, vB ? sB : -1e30f);
        float scB = __expf(mB - mnB);
        float pB  = vB ? __expf(sB - mnB) : 0.0f;
        mB = mnB; lB = lB * scB + pB;
        float vf[16];
        unpack16((const u32*)&vs[row * ASTR + g * 18], vf);
#pragma unroll
        for (int d = 0; d < 16; ++d) {
            accA[d] = accA[d] * scA + pA * vf[d];
            accB[d] = accB[d] * scB + pB * vf[d];
        }
    }

    float invA = 1.0f / lA;
    float invB = 1.0f / lB;
    u32 oA[8], oB[8];
#pragma unroll
    for (int j2 = 0; j2 < 8; ++j2) {
        oA[j2] = (u32)f2bf(accA[2 * j2] * invA) | ((u32)f2bf(accA[2 * j2 + 1] * invA) << 16);
        oB[j2] = (u32)f2bf(accB[2 * j2] * invB) | ((u32)f2bf(accB[2 * j2 + 1] * invB) << 16);
    }
    u16* poA = out + rowA * D_MOD + h * HDIM + g * 16;
    u16* poB = out + rowB * D_MOD + h * HDIM + g * 16;
    *(uint4*)poA       = make_uint4(oA[0], oA[1], oA[2], oA[3]);
    *(uint4*)(poA + 8) = make_uint4(oA[4], oA[5], oA[6], oA[7]);
    *(uint4*)poB       = make_uint4(oB[0], oB[1], oB[2], oB[3]);
    *(uint4*)(poB + 8) = make_uint4(oB[4], oB[5], oB[6], oB[7]);
}

// ---------------- launch ----------------
extern "C" void kernel_launch(void* const* d_in, const int* in_sizes, int n_in,
                              void* d_out, int out_size, void* d_ws, size_t ws_size,
                              hipStream_t stream)
{
    (void)in_sizes; (void)n_in; (void)out_size; (void)ws_size;
    const float* x      = (const float*)d_in[0];
    const float* radius = (const float*)d_in[1];
    const float* w_in   = (const float*)d_in[2];
    const float* b_in   = (const float*)d_in[3];
    const float* w_out  = (const float*)d_in[4];
    const float* b_out  = (const float*)d_in[5];
    float* outp = (float*)d_out;

    char* ws = (char*)d_ws;
    u16* x_bf    = (u16*)ws;  ws += (size_t)M_ROWS * D_MOD * 2;
    u16* win_bf  = (u16*)ws;  ws += (size_t)QKV_N * D_MOD * 2;
    u16* wout_bf = (u16*)ws;  ws += (size_t)D_MOD * D_MOD * 2;
    u16* qkv_bf  = (u16*)ws;  ws += (size_t)M_ROWS * QKV_N * 2;
    u16* attn_bf = (u16*)ws;

    const int na = M_ROWS * D_MOD;        // 4194304
    const int nb = QKV_N * D_MOD;         // 786432
    const int nc = D_MOD * D_MOD;         // 262144
    cast3_kernel<<<(na + nb + nc) / 2048, 256, 0, stream>>>(
        x, na, w_in, nb, w_out, x_bf, win_bf, wout_bf);

    gemm_bt<true, 128, 192><<<dim3(QKV_N / 192, M_ROWS / 128), 256, 0, stream>>>(
        x_bf, win_bf, b_in, qkv_bf, M_ROWS, QKV_N, D_MOD);
    attn_kernel<<<B_SZ * N_HEAD * (T_LEN / AQ), 256, 0, stream>>>(qkv_bf, radius, attn_bf);
    gemm_bt<false, 64, 128><<<dim3(D_MOD / 128, M_ROWS / 64), 256, 0, stream>>>(
        attn_bf, wout_bf, b_out, outp, M_ROWS, D_MOD, D_MOD);
}